// Round 1
// baseline (421.332 us; speedup 1.0000x reference)
//
#include <hip/hip_runtime.h>

#define CAP 64

// ---------------------------------------------------------------------------
// K1: bucketed adjacency build. For each edge (a,b): append b to adj[a], a to
// adj[b]. 1.2M int atomics instead of 153.6M float atomics.
// ---------------------------------------------------------------------------
__global__ void fill_adj_kernel(const int* __restrict__ ra,
                                const int* __restrict__ rb,
                                int* __restrict__ cnt,
                                int* __restrict__ adj,
                                int nedges) {
  int e = blockIdx.x * blockDim.x + threadIdx.x;
  if (e >= nedges) return;
  int a = ra[e];
  int b = rb[e];
  int pa = atomicAdd(&cnt[a], 1);
  if (pa < CAP) adj[(size_t)a * CAP + pa] = b;
  int pb = atomicAdd(&cnt[b], 1);
  if (pb < CAP) adj[(size_t)b * CAP + pb] = a;
}

// ---------------------------------------------------------------------------
// K2: gather-aggregate. One wave (64 lanes) per node, lane i holds feats
// [2i,2i+1] as float2. agg = X[node] + sum of neighbor rows. Writes into
// d_out (used as X_agg storage; fused_mlp reads-then-overwrites its own rows).
// ---------------------------------------------------------------------------
__global__ void gather_agg_kernel(const float* __restrict__ X,
                                  const int* __restrict__ cnt,
                                  const int* __restrict__ adj,
                                  float* __restrict__ agg,
                                  int nnodes) {
  int gid = blockIdx.x * blockDim.x + threadIdx.x;
  int node = gid >> 6;
  int lane = gid & 63;
  if (node >= nnodes) return;
  const float2* Xv = (const float2*)X;
  float2 acc = Xv[(size_t)node * 64 + lane];
  int n = cnt[node];
  if (n > CAP) n = CAP;
  const int* lst = adj + (size_t)node * CAP;
  int k = 0;
  for (; k + 4 <= n; k += 4) {  // 4 loads in flight to hide L2/L3 latency
    int n0 = lst[k + 0];
    int n1 = lst[k + 1];
    int n2 = lst[k + 2];
    int n3 = lst[k + 3];
    float2 v0 = Xv[(size_t)n0 * 64 + lane];
    float2 v1 = Xv[(size_t)n1 * 64 + lane];
    float2 v2 = Xv[(size_t)n2 * 64 + lane];
    float2 v3 = Xv[(size_t)n3 * 64 + lane];
    acc.x += v0.x + v1.x + v2.x + v3.x;
    acc.y += v0.y + v1.y + v2.y + v3.y;
  }
  for (; k < n; ++k) {
    int nb = lst[k];
    float2 v = Xv[(size_t)nb * 64 + lane];
    acc.x += v.x;
    acc.y += v.y;
  }
  ((float2*)agg)[(size_t)node * 64 + lane] = acc;
}

// ---------------------------------------------------------------------------
// Fallback aggregation if workspace is too small for adjacency buckets:
// fp32 atomics straight into agg (pre-initialized with X via d2d copy).
// ---------------------------------------------------------------------------
__global__ void atomic_agg_kernel(const float* __restrict__ X,
                                  const int* __restrict__ ra,
                                  const int* __restrict__ rb,
                                  float* agg, int nedges) {
  long long gid = (long long)blockIdx.x * blockDim.x + threadIdx.x;
  int e = (int)(gid >> 5);
  int q = (int)(gid & 31);
  if (e >= nedges) return;
  int a = ra[e];
  int b = rb[e];
  float4 xb = *(const float4*)(X + (size_t)b * 128 + q * 4);
  float4 xa = *(const float4*)(X + (size_t)a * 128 + q * 4);
  float* pa = agg + (size_t)a * 128 + q * 4;
  float* pb = agg + (size_t)b * 128 + q * 4;
  atomicAdd(pa + 0, xb.x);
  atomicAdd(pa + 1, xb.y);
  atomicAdd(pa + 2, xb.z);
  atomicAdd(pa + 3, xb.w);
  atomicAdd(pb + 0, xa.x);
  atomicAdd(pb + 1, xa.y);
  atomicAdd(pb + 2, xa.z);
  atomicAdd(pb + 3, xa.w);
}

// ---------------------------------------------------------------------------
// K3: fused  out = relu(Xagg @ Wh + bh) @ Wo + bo,  fp32 vector ALU.
// Block: 256 threads, 128-row x 128-col tile. Thread: 8x8 register tile for
// GEMM1 (rg=tid>>4 rows, cg=tid&15 cols). LDS = 64KB exactly:
//   phase1: sA = Xagg tile [128][64] (K-chunked), sB = Wh chunk [64][128]
//   phase2: sA = hidden tile [64][128] (two 64-row halves), sB = Wo chunk
// Xagg is read from and the result written to the SAME buffer (io == d_out);
// each block only touches its own 128 rows, reads complete before writes.
// ---------------------------------------------------------------------------
__global__ __launch_bounds__(256) void fused_mlp_kernel(
    float* io, const float* __restrict__ Wh, const float* __restrict__ bh,
    const float* __restrict__ Wo, const float* __restrict__ bo, int nnodes) {
  __shared__ float smem[16384];  // 64 KB
  float* sA = smem;              // 8192 floats
  float* sB = smem + 8192;       // 8192 floats

  const int tid = threadIdx.x;
  const int r0 = blockIdx.x * 128;
  const int rg = tid >> 4;   // 0..15
  const int cg = tid & 15;   // 0..15
  const int cbase = cg * 8;

  float acc1[8][8];
#pragma unroll
  for (int i = 0; i < 8; ++i)
#pragma unroll
    for (int j = 0; j < 8; ++j) acc1[i][j] = 0.f;

  // ---------------- phase 1: hidden = Xagg @ Wh ----------------
  for (int kc = 0; kc < 128; kc += 64) {
#pragma unroll
    for (int t = 0; t < 8; ++t) {  // load Xagg tile 128x64
      int i = tid + t * 256;
      int r = i >> 4;
      int c4 = (i & 15) << 2;
      int gr = r0 + r;
      if (gr >= nnodes) gr = nnodes - 1;
      *(float4*)(sA + r * 64 + c4) =
          *(const float4*)(io + (size_t)gr * 128 + kc + c4);
    }
#pragma unroll
    for (int t = 0; t < 8; ++t) {  // load Wh chunk 64x128
      int i = tid + t * 256;
      int r = i >> 5;
      int c4 = (i & 31) << 2;
      *(float4*)(sB + r * 128 + c4) =
          *(const float4*)(Wh + (size_t)(kc + r) * 128 + c4);
    }
    __syncthreads();
#pragma unroll 2
    for (int k4 = 0; k4 < 64; k4 += 4) {
      float4 av[8];
#pragma unroll
      for (int i = 0; i < 8; ++i)
        av[i] = *(const float4*)(sA + (rg * 8 + i) * 64 + k4);
#pragma unroll
      for (int kk = 0; kk < 4; ++kk) {
        float4 b0 = *(const float4*)(sB + (k4 + kk) * 128 + cbase);
        float4 b1 = *(const float4*)(sB + (k4 + kk) * 128 + cbase + 4);
        float bb[8] = {b0.x, b0.y, b0.z, b0.w, b1.x, b1.y, b1.z, b1.w};
#pragma unroll
        for (int i = 0; i < 8; ++i) {
          float a = (kk == 0)   ? av[i].x
                    : (kk == 1) ? av[i].y
                    : (kk == 2) ? av[i].z
                                : av[i].w;
#pragma unroll
          for (int j = 0; j < 8; ++j) acc1[i][j] = fmaf(a, bb[j], acc1[i][j]);
        }
      }
    }
    __syncthreads();
  }

  // bias + relu in place
  {
    float4 q0 = *(const float4*)(bh + cbase);
    float4 q1 = *(const float4*)(bh + cbase + 4);
    float bv[8] = {q0.x, q0.y, q0.z, q0.w, q1.x, q1.y, q1.z, q1.w};
#pragma unroll
    for (int i = 0; i < 8; ++i)
#pragma unroll
      for (int j = 0; j < 8; ++j) acc1[i][j] = fmaxf(acc1[i][j] + bv[j], 0.f);
  }
  float bov[8];
  {
    float4 q0 = *(const float4*)(bo + cbase);
    float4 q1 = *(const float4*)(bo + cbase + 4);
    bov[0] = q0.x; bov[1] = q0.y; bov[2] = q0.z; bov[3] = q0.w;
    bov[4] = q1.x; bov[5] = q1.y; bov[6] = q1.z; bov[7] = q1.w;
  }

  // ---------------- phase 2: out = hidden @ Wo, two 64-row halves ---------
  const int rg2 = tid >> 4;  // 0..15 -> 4 rows each of the 64-row half
  for (int hh = 0; hh < 2; ++hh) {
    if ((rg >> 3) == hh) {  // this half's owners write hidden -> sA[64][128]
      int lrg = rg & 7;
#pragma unroll
      for (int i = 0; i < 8; ++i) {
        int lr = lrg * 8 + i;
        *(float4*)(sA + lr * 128 + cbase) =
            make_float4(acc1[i][0], acc1[i][1], acc1[i][2], acc1[i][3]);
        *(float4*)(sA + lr * 128 + cbase + 4) =
            make_float4(acc1[i][4], acc1[i][5], acc1[i][6], acc1[i][7]);
      }
    }
    __syncthreads();

    float acc2[4][8];
#pragma unroll
    for (int i = 0; i < 4; ++i)
#pragma unroll
      for (int j = 0; j < 8; ++j) acc2[i][j] = 0.f;

    for (int kc2 = 0; kc2 < 128; kc2 += 64) {
#pragma unroll
      for (int t = 0; t < 8; ++t) {  // load Wo chunk 64x128
        int i = tid + t * 256;
        int r = i >> 5;
        int c4 = (i & 31) << 2;
        *(float4*)(sB + r * 128 + c4) =
            *(const float4*)(Wo + (size_t)(kc2 + r) * 128 + c4);
      }
      __syncthreads();
#pragma unroll 2
      for (int k4 = 0; k4 < 64; k4 += 4) {
        float4 av[4];
#pragma unroll
        for (int i = 0; i < 4; ++i)
          av[i] = *(const float4*)(sA + (rg2 * 4 + i) * 128 + kc2 + k4);
#pragma unroll
        for (int kk = 0; kk < 4; ++kk) {
          float4 b0 = *(const float4*)(sB + (k4 + kk) * 128 + cbase);
          float4 b1 = *(const float4*)(sB + (k4 + kk) * 128 + cbase + 4);
          float bb[8] = {b0.x, b0.y, b0.z, b0.w, b1.x, b1.y, b1.z, b1.w};
#pragma unroll
          for (int i = 0; i < 4; ++i) {
            float a = (kk == 0)   ? av[i].x
                      : (kk == 1) ? av[i].y
                      : (kk == 2) ? av[i].z
                                  : av[i].w;
#pragma unroll
            for (int j = 0; j < 8; ++j)
              acc2[i][j] = fmaf(a, bb[j], acc2[i][j]);
          }
        }
      }
      __syncthreads();
    }

#pragma unroll
    for (int i = 0; i < 4; ++i) {
      int gr = r0 + hh * 64 + rg2 * 4 + i;
      if (gr < nnodes) {
        *(float4*)(io + (size_t)gr * 128 + cbase) =
            make_float4(acc2[i][0] + bov[0], acc2[i][1] + bov[1],
                        acc2[i][2] + bov[2], acc2[i][3] + bov[3]);
        *(float4*)(io + (size_t)gr * 128 + cbase + 4) =
            make_float4(acc2[i][4] + bov[4], acc2[i][5] + bov[5],
                        acc2[i][6] + bov[6], acc2[i][7] + bov[7]);
      }
    }
  }
}

// ---------------------------------------------------------------------------
extern "C" void kernel_launch(void* const* d_in, const int* in_sizes, int n_in,
                              void* d_out, int out_size, void* d_ws,
                              size_t ws_size, hipStream_t stream) {
  const float* X = (const float*)d_in[0];
  const int* ra = (const int*)d_in[1];
  const int* rb = (const int*)d_in[2];
  const float* Wh = (const float*)d_in[3];
  const float* bh = (const float*)d_in[4];
  const float* Wo = (const float*)d_in[5];
  const float* bo = (const float*)d_in[6];
  float* out = (float*)d_out;

  int nnodes = in_sizes[0] / 128;
  int nedges = in_sizes[1];

  size_t need = (size_t)nnodes * 4 + (size_t)nnodes * CAP * 4;
  if (ws_size >= need) {
    int* cnt = (int*)d_ws;
    int* adj = cnt + nnodes;
    hipMemsetAsync(cnt, 0, (size_t)nnodes * 4, stream);
    fill_adj_kernel<<<(nedges + 255) / 256, 256, 0, stream>>>(ra, rb, cnt, adj,
                                                              nedges);
    gather_agg_kernel<<<(nnodes * 64 + 255) / 256, 256, 0, stream>>>(
        X, cnt, adj, out, nnodes);
  } else {
    hipMemcpyAsync(out, X, (size_t)nnodes * 128 * 4, hipMemcpyDeviceToDevice,
                   stream);
    atomic_agg_kernel<<<(int)(((long long)nedges * 32 + 255) / 256), 256, 0,
                        stream>>>(X, ra, rb, out, nedges);
  }
  fused_mlp_kernel<<<(nnodes + 127) / 128, 256, 0, stream>>>(out, Wh, bh, Wo,
                                                             bo, nnodes);
}

// Round 2
// 286.263 us; speedup vs baseline: 1.4718x; 1.4718x over previous
//
#include <hip/hip_runtime.h>

#define CAP 64

typedef short bf16x8 __attribute__((ext_vector_type(8)));
typedef float f32x4 __attribute__((ext_vector_type(4)));
typedef unsigned short u16;
typedef unsigned int u32;

__device__ __forceinline__ u16 f32_to_bf16(float f) {
  u32 b = __float_as_uint(f);
  b += 0x7fffu + ((b >> 16) & 1u);  // round to nearest even
  return (u16)(b >> 16);
}

// ---------------------------------------------------------------------------
// K1: bucketed adjacency build. One thread per (edge, direction) -> shorter
// dependency chain per thread. 1.2M int atomics + 2.4M scattered 4B stores.
// ---------------------------------------------------------------------------
__global__ void fill_adj_kernel(const int* __restrict__ ra,
                                const int* __restrict__ rb,
                                int* __restrict__ cnt,
                                int* __restrict__ adj,
                                int nedges) {
  int gid = blockIdx.x * blockDim.x + threadIdx.x;
  int e = gid >> 1;
  if (e >= nedges) return;
  int src, dst;
  if (gid & 1) { src = ra[e]; dst = rb[e]; }
  else         { src = rb[e]; dst = ra[e]; }
  int p = atomicAdd(&cnt[dst], 1);
  if (p < CAP) adj[(size_t)dst * CAP + p] = src;
}

// ---------------------------------------------------------------------------
// K2: gather-aggregate. One wave per node, lane i holds feats [2i,2i+1]
// (float2). Accumulate in fp32, then write the 128-elem row as bf16 INTO THE
// NODE'S OWN ADJ BUCKET (64 ints = 256 B = exactly one bf16 row). The bucket
// is fully consumed (data dependency through acc) before the store; buckets
// are disjoint across nodes -> race-free, zero extra workspace.
// ---------------------------------------------------------------------------
__global__ void gather_agg_kernel(const float* __restrict__ X,
                                  const int* __restrict__ cnt,
                                  int* __restrict__ adj,
                                  int nnodes) {
  int gid = blockIdx.x * blockDim.x + threadIdx.x;
  int node = gid >> 6;
  int lane = gid & 63;
  if (node >= nnodes) return;
  const float2* Xv = (const float2*)X;
  float2 acc = Xv[(size_t)node * 64 + lane];
  int n = cnt[node];
  if (n > CAP) n = CAP;
  const int* lst = adj + (size_t)node * CAP;
  int k = 0;
  for (; k + 4 <= n; k += 4) {  // 4 row-loads in flight to hide L2/L3 latency
    int n0 = lst[k + 0];
    int n1 = lst[k + 1];
    int n2 = lst[k + 2];
    int n3 = lst[k + 3];
    float2 v0 = Xv[(size_t)n0 * 64 + lane];
    float2 v1 = Xv[(size_t)n1 * 64 + lane];
    float2 v2 = Xv[(size_t)n2 * 64 + lane];
    float2 v3 = Xv[(size_t)n3 * 64 + lane];
    acc.x += v0.x + v1.x + v2.x + v3.x;
    acc.y += v0.y + v1.y + v2.y + v3.y;
  }
  for (; k < n; ++k) {
    int nb = lst[k];
    float2 v = Xv[(size_t)nb * 64 + lane];
    acc.x += v.x;
    acc.y += v.y;
  }
  u32 pk = (u32)f32_to_bf16(acc.x) | ((u32)f32_to_bf16(acc.y) << 16);
  ((u32*)adj)[(size_t)node * 64 + lane] = pk;  // bf16 row, elems [2i,2i+1]
}

// ---------------------------------------------------------------------------
// K3: transpose+convert weights fp32 -> bf16 (W^T layout [n][k]) into the
// dead `cnt` region (runs after gather). grid 128 x 256 covers both matrices.
// ---------------------------------------------------------------------------
__global__ void convert_w_kernel(const float* __restrict__ Wh,
                                 const float* __restrict__ Wo,
                                 u16* __restrict__ WhT,
                                 u16* __restrict__ WoT) {
  int idx = blockIdx.x * 256 + threadIdx.x;  // 0..32767
  const float* src = (idx < 16384) ? Wh : Wo;
  u16* dst = (idx < 16384) ? WhT : WoT;
  int i = idx & 16383;
  int k = i >> 7, n = i & 127;
  dst[n * 128 + k] = f32_to_bf16(src[k * 128 + n]);
}

// ---------------------------------------------------------------------------
// K4: fused MLP via bf16 MFMA (16x16x32).
//   out = relu(Xagg @ Wh + bh) @ Wo + bo
// Block: 256 threads = 4 waves; 128-row x 128-col tile.
// Wave w: rows [w*32, w*32+32) = 2 m-tiles x 8 n-tiles, acc = 16 f32x4.
// LDS: sA[128x128 bf16] (activations), sW[128x128 bf16] (W^T) = 64 KB total,
// both XOR-swizzled in 16B units: phys_unit = u ^ (row & 15)  -> both A- and
// B-fragment ds_read_b128 are 2-way bank-aliased (free, m136).
// Fragment layouts (m89/m120): A[m=lane&15][k=(lane>>4)*8+j] (8 contiguous k
// = one 16B unit); B[k][n=lane&15] same k-unit from W^T row n;
// C/D: col=lane&15, row=(lane>>4)*4+reg.
// sA rows are per-wave-exclusive (read + hidden write) -> only sW restaging
// needs the two syncthreads.
// ---------------------------------------------------------------------------
__global__ __launch_bounds__(256) void mlp_mfma_kernel(
    const u16* __restrict__ Xagg,  // [nnodes][128] bf16 (lives in adj region)
    const u16* __restrict__ WhT,   // [128][128] bf16, [n][k]
    const u16* __restrict__ WoT,   // [128][128] bf16, [n][k]
    const float* __restrict__ bh,
    const float* __restrict__ bo,
    float* __restrict__ out, int nnodes) {
  __shared__ u16 sA[128 * 128];
  __shared__ u16 sW[128 * 128];

  const int tid = threadIdx.x;
  const int w = tid >> 6;
  const int l = tid & 63;
  const int l15 = l & 15;
  const int l4 = l >> 4;  // quad 0..3
  const int r0 = blockIdx.x * 128;

  // ---- stage sA (Xagg tile) and sW (Wh^T), swizzled ----
#pragma unroll
  for (int t = 0; t < 8; ++t) {
    int id = tid + t * 256;  // 0..2047 : 128 rows x 16 units
    int r = id >> 4, u = id & 15;
    int gr = r0 + r;
    if (gr >= nnodes) gr = nnodes - 1;
    *(int4*)&sA[r * 128 + ((u ^ (r & 15)) * 8)] =
        *(const int4*)&Xagg[(size_t)gr * 128 + u * 8];
    *(int4*)&sW[r * 128 + ((u ^ (r & 15)) * 8)] =
        *(const int4*)&WhT[r * 128 + u * 8];
  }

  float bhv[8], bov[8];
#pragma unroll
  for (int j = 0; j < 8; ++j) {
    bhv[j] = bh[j * 16 + l15];
    bov[j] = bo[j * 16 + l15];
  }
  __syncthreads();

  const int m0 = w * 32 + l15;        // A row, m-tile 0
  const int m1 = w * 32 + 16 + l15;   // A row, m-tile 1

  f32x4 acc[2][8];
#pragma unroll
  for (int i = 0; i < 2; ++i)
#pragma unroll
    for (int j = 0; j < 8; ++j) acc[i][j] = (f32x4){0.f, 0.f, 0.f, 0.f};

  // ---- GEMM1: hidden = Xagg @ Wh ----
#pragma unroll
  for (int c = 0; c < 4; ++c) {  // K chunks of 32
    int pu = ((c * 4 + l4) ^ l15) * 8;
    bf16x8 a0 = *(bf16x8*)&sA[m0 * 128 + pu];
    bf16x8 a1 = *(bf16x8*)&sA[m1 * 128 + pu];
#pragma unroll
    for (int j = 0; j < 8; ++j) {
      bf16x8 bfr = *(bf16x8*)&sW[(j * 16 + l15) * 128 + pu];
      acc[0][j] = __builtin_amdgcn_mfma_f32_16x16x32_bf16(a0, bfr, acc[0][j], 0, 0, 0);
      acc[1][j] = __builtin_amdgcn_mfma_f32_16x16x32_bf16(a1, bfr, acc[1][j], 0, 0, 0);
    }
  }

  __syncthreads();  // all waves done reading sW (GEMM1)

  // ---- restage sW with Wo^T ----
#pragma unroll
  for (int t = 0; t < 8; ++t) {
    int id = tid + t * 256;
    int r = id >> 4, u = id & 15;
    *(int4*)&sW[r * 128 + ((u ^ (r & 15)) * 8)] =
        *(const int4*)&WoT[r * 128 + u * 8];
  }

  // ---- bias + relu + bf16, write hidden into sA (own rows only) ----
#pragma unroll
  for (int i = 0; i < 2; ++i)
#pragma unroll
    for (int j = 0; j < 8; ++j)
#pragma unroll
      for (int r = 0; r < 4; ++r) {
        int m = w * 32 + i * 16 + l4 * 4 + r;
        float v = fmaxf(acc[i][j][r] + bhv[j], 0.f);
        int k = j * 16 + l15;
        sA[m * 128 + (((k >> 3) ^ (m & 15)) * 8) + (k & 7)] = f32_to_bf16(v);
      }
  __syncthreads();

  // ---- GEMM2: out = hidden @ Wo (reuse acc) ----
#pragma unroll
  for (int i = 0; i < 2; ++i)
#pragma unroll
    for (int j = 0; j < 8; ++j) acc[i][j] = (f32x4){0.f, 0.f, 0.f, 0.f};

#pragma unroll
  for (int c = 0; c < 4; ++c) {
    int pu = ((c * 4 + l4) ^ l15) * 8;
    bf16x8 a0 = *(bf16x8*)&sA[m0 * 128 + pu];
    bf16x8 a1 = *(bf16x8*)&sA[m1 * 128 + pu];
#pragma unroll
    for (int j = 0; j < 8; ++j) {
      bf16x8 bfr = *(bf16x8*)&sW[(j * 16 + l15) * 128 + pu];
      acc[0][j] = __builtin_amdgcn_mfma_f32_16x16x32_bf16(a0, bfr, acc[0][j], 0, 0, 0);
      acc[1][j] = __builtin_amdgcn_mfma_f32_16x16x32_bf16(a1, bfr, acc[1][j], 0, 0, 0);
    }
  }

  // ---- epilogue: + bo, fp32 store ----
#pragma unroll
  for (int i = 0; i < 2; ++i)
#pragma unroll
    for (int r = 0; r < 4; ++r) {
      int gr = r0 + w * 32 + i * 16 + l4 * 4 + r;
      if (gr < nnodes) {
#pragma unroll
        for (int j = 0; j < 8; ++j)
          out[(size_t)gr * 128 + j * 16 + l15] = acc[i][j][r] + bov[j];
      }
    }
}

// ---------------------------------------------------------------------------
extern "C" void kernel_launch(void* const* d_in, const int* in_sizes, int n_in,
                              void* d_out, int out_size, void* d_ws,
                              size_t ws_size, hipStream_t stream) {
  const float* X = (const float*)d_in[0];
  const int* ra = (const int*)d_in[1];
  const int* rb = (const int*)d_in[2];
  const float* Wh = (const float*)d_in[3];
  const float* bh = (const float*)d_in[4];
  const float* Wo = (const float*)d_in[5];
  const float* bo = (const float*)d_in[6];
  float* out = (float*)d_out;

  int nnodes = in_sizes[0] / 128;
  int nedges = in_sizes[1];

  // ws layout: [cnt: nnodes ints | adj: nnodes*CAP ints]
  // after gather: adj region holds Xagg bf16 rows (node*256B);
  //               cnt region is dead -> reused for WhT/WoT bf16.
  int* cnt = (int*)d_ws;
  int* adj = cnt + nnodes;
  u16* WhT = (u16*)d_ws;
  u16* WoT = WhT + 16384;

  hipMemsetAsync(cnt, 0, (size_t)nnodes * 4, stream);
  fill_adj_kernel<<<(2 * nedges + 255) / 256, 256, 0, stream>>>(ra, rb, cnt,
                                                                adj, nedges);
  gather_agg_kernel<<<(nnodes * 64 + 255) / 256, 256, 0, stream>>>(X, cnt, adj,
                                                                   nnodes);
  convert_w_kernel<<<128, 256, 0, stream>>>(Wh, Wo, WhT, WoT);
  mlp_mfma_kernel<<<(nnodes + 127) / 128, 256, 0, stream>>>(
      (const u16*)adj, WhT, WoT, bh, bo, out, nnodes);
}

// Round 3
// 260.424 us; speedup vs baseline: 1.6179x; 1.0992x over previous
//
#include <hip/hip_runtime.h>

#define CAP 64

typedef short bf16x8 __attribute__((ext_vector_type(8)));
typedef float f32x4 __attribute__((ext_vector_type(4)));
typedef unsigned short u16;
typedef unsigned int u32;

__device__ __forceinline__ u16 f32_to_bf16(float f) {
  u32 b = __float_as_uint(f);
  b += 0x7fffu + ((b >> 16) & 1u);  // round to nearest even
  return (u16)(b >> 16);
}

// ---------------------------------------------------------------------------
// K0: X fp32 -> bf16, packed into d_out's first 25.6 MB (dead until mlp
// overwrites it, after gather has consumed it). 8 elems/thread, int4 stores.
// ---------------------------------------------------------------------------
__global__ void convert_x_kernel(const float* __restrict__ X,
                                 u16* __restrict__ Xb, int n8) {
  int i = blockIdx.x * blockDim.x + threadIdx.x;
  if (i >= n8) return;
  float4 a = ((const float4*)X)[2 * i];
  float4 b = ((const float4*)X)[2 * i + 1];
  int4 o;
  o.x = (int)((u32)f32_to_bf16(a.x) | ((u32)f32_to_bf16(a.y) << 16));
  o.y = (int)((u32)f32_to_bf16(a.z) | ((u32)f32_to_bf16(a.w) << 16));
  o.z = (int)((u32)f32_to_bf16(b.x) | ((u32)f32_to_bf16(b.y) << 16));
  o.w = (int)((u32)f32_to_bf16(b.z) | ((u32)f32_to_bf16(b.w) << 16));
  ((int4*)Xb)[i] = o;
}

// ---------------------------------------------------------------------------
// K1: bucketed adjacency build. One thread per (edge, direction).
// ---------------------------------------------------------------------------
__global__ void fill_adj_kernel(const int* __restrict__ ra,
                                const int* __restrict__ rb,
                                int* __restrict__ cnt,
                                int* __restrict__ adj,
                                int nedges) {
  int gid = blockIdx.x * blockDim.x + threadIdx.x;
  int e = gid >> 1;
  if (e >= nedges) return;
  int src, dst;
  if (gid & 1) { src = ra[e]; dst = rb[e]; }
  else         { src = rb[e]; dst = ra[e]; }
  int p = atomicAdd(&cnt[dst], 1);
  if (p < CAP) adj[(size_t)dst * CAP + p] = src;
}

// ---------------------------------------------------------------------------
// K2: gather-aggregate over bf16 X. One wave per node; lane i holds feats
// [2i,2i+1] as one u32 (2 bf16). Indices loaded once coalesced (lst[lane])
// and broadcast via __shfl; row loads unrolled 8-deep (2 KB in flight/wave).
// fp32 accumulate; result written as a bf16 row into the node's own adj
// bucket (256 B, fully consumed before the store; buckets disjoint).
// ---------------------------------------------------------------------------
__global__ void gather_agg_kernel(const u16* __restrict__ Xb,
                                  const int* __restrict__ cnt,
                                  int* __restrict__ adj,
                                  int nnodes) {
  int gid = blockIdx.x * blockDim.x + threadIdx.x;
  int node = gid >> 6;
  int lane = gid & 63;
  if (node >= nnodes) return;
  const u32* Xv = (const u32*)Xb;  // row stride 64 u32
  const int* lst = adj + (size_t)node * CAP;
  int myidx = lst[lane];  // one coalesced 256B load per wave
  int n = cnt[node];
  if (n > CAP) n = CAP;
  u32 ps = Xv[(size_t)node * 64 + lane];
  float2 acc;
  acc.x = __uint_as_float(ps << 16);
  acc.y = __uint_as_float(ps & 0xffff0000u);
  int k = 0;
  for (; k + 8 <= n; k += 8) {
    u32 p[8];
#pragma unroll
    for (int t = 0; t < 8; ++t) {
      int nb = __shfl(myidx, k + t);
      p[t] = Xv[(size_t)nb * 64 + lane];
    }
#pragma unroll
    for (int t = 0; t < 8; ++t) {
      acc.x += __uint_as_float(p[t] << 16);
      acc.y += __uint_as_float(p[t] & 0xffff0000u);
    }
  }
  for (; k < n; ++k) {
    int nb = __shfl(myidx, k);
    u32 p = Xv[(size_t)nb * 64 + lane];
    acc.x += __uint_as_float(p << 16);
    acc.y += __uint_as_float(p & 0xffff0000u);
  }
  u32 pk = (u32)f32_to_bf16(acc.x) | ((u32)f32_to_bf16(acc.y) << 16);
  ((u32*)adj)[(size_t)node * 64 + lane] = pk;
}

// ---------------------------------------------------------------------------
// K3: transpose+convert weights fp32 -> bf16 (W^T layout [n][k]) into the
// dead `cnt` region (runs after gather).
// ---------------------------------------------------------------------------
__global__ void convert_w_kernel(const float* __restrict__ Wh,
                                 const float* __restrict__ Wo,
                                 u16* __restrict__ WhT,
                                 u16* __restrict__ WoT) {
  int idx = blockIdx.x * 256 + threadIdx.x;  // 0..32767
  const float* src = (idx < 16384) ? Wh : Wo;
  u16* dst = (idx < 16384) ? WhT : WoT;
  int i = idx & 16383;
  int k = i >> 7, n = i & 127;
  dst[n * 128 + k] = f32_to_bf16(src[k * 128 + n]);
}

// ---------------------------------------------------------------------------
// K4: fused MLP via bf16 MFMA (16x16x32).
//   out = relu(Xagg @ Wh + bh) @ Wo + bo
// 256 threads = 4 waves; 128x128 row tile; wave w owns rows [w*32,w*32+32).
// LDS: one 64 KB buffer: sA (activations, XOR-swizzled 16B units) +
// sW (W^T, same swizzle). Epilogue: all 128x128 fp32 outputs staged in the
// same 64 KB (after barrier) and stored with coalesced dwordx4.
// Fragment layouts (m89/m120): A[m=lane&15][k=(lane>>4)*8+j];
// B[k][n=lane&15] from W^T row n; C/D col=lane&15, row=(lane>>4)*4+reg.
// ---------------------------------------------------------------------------
__global__ __launch_bounds__(256) void mlp_mfma_kernel(
    const u16* __restrict__ Xagg,  // [nnodes][128] bf16 (lives in adj region)
    const u16* __restrict__ WhT,   // [128][128] bf16, [n][k]
    const u16* __restrict__ WoT,   // [128][128] bf16, [n][k]
    const float* __restrict__ bh,
    const float* __restrict__ bo,
    float* __restrict__ out, int nnodes) {
  __shared__ u16 smem[2 * 128 * 128];  // 64 KB
  u16* sA = smem;
  u16* sW = smem + 16384;

  const int tid = threadIdx.x;
  const int w = tid >> 6;
  const int l = tid & 63;
  const int l15 = l & 15;
  const int l4 = l >> 4;  // quad 0..3
  const int r0 = blockIdx.x * 128;

  // ---- stage sA (Xagg tile) and sW (Wh^T), swizzled ----
#pragma unroll
  for (int t = 0; t < 8; ++t) {
    int id = tid + t * 256;  // 0..2047 : 128 rows x 16 units
    int r = id >> 4, u = id & 15;
    int gr = r0 + r;
    if (gr >= nnodes) gr = nnodes - 1;
    *(int4*)&sA[r * 128 + ((u ^ (r & 15)) * 8)] =
        *(const int4*)&Xagg[(size_t)gr * 128 + u * 8];
    *(int4*)&sW[r * 128 + ((u ^ (r & 15)) * 8)] =
        *(const int4*)&WhT[r * 128 + u * 8];
  }

  float bhv[8], bov[8];
#pragma unroll
  for (int j = 0; j < 8; ++j) {
    bhv[j] = bh[j * 16 + l15];
    bov[j] = bo[j * 16 + l15];
  }
  __syncthreads();

  const int m0 = w * 32 + l15;       // A row, m-tile 0
  const int m1 = w * 32 + 16 + l15;  // A row, m-tile 1

  f32x4 acc[2][8];
#pragma unroll
  for (int i = 0; i < 2; ++i)
#pragma unroll
    for (int j = 0; j < 8; ++j) acc[i][j] = (f32x4){0.f, 0.f, 0.f, 0.f};

  // ---- GEMM1: hidden = Xagg @ Wh ----
#pragma unroll
  for (int c = 0; c < 4; ++c) {  // K chunks of 32
    int pu = ((c * 4 + l4) ^ l15) * 8;
    bf16x8 a0 = *(bf16x8*)&sA[m0 * 128 + pu];
    bf16x8 a1 = *(bf16x8*)&sA[m1 * 128 + pu];
#pragma unroll
    for (int j = 0; j < 8; ++j) {
      bf16x8 bfr = *(bf16x8*)&sW[(j * 16 + l15) * 128 + pu];
      acc[0][j] = __builtin_amdgcn_mfma_f32_16x16x32_bf16(a0, bfr, acc[0][j], 0, 0, 0);
      acc[1][j] = __builtin_amdgcn_mfma_f32_16x16x32_bf16(a1, bfr, acc[1][j], 0, 0, 0);
    }
  }

  __syncthreads();  // all waves done reading sW (GEMM1)

  // ---- restage sW with Wo^T ----
#pragma unroll
  for (int t = 0; t < 8; ++t) {
    int id = tid + t * 256;
    int r = id >> 4, u = id & 15;
    *(int4*)&sW[r * 128 + ((u ^ (r & 15)) * 8)] =
        *(const int4*)&WoT[r * 128 + u * 8];
  }

  // ---- bias + relu + bf16, write hidden into sA (own rows only) ----
#pragma unroll
  for (int i = 0; i < 2; ++i)
#pragma unroll
    for (int j = 0; j < 8; ++j)
#pragma unroll
      for (int r = 0; r < 4; ++r) {
        int m = w * 32 + i * 16 + l4 * 4 + r;
        float v = fmaxf(acc[i][j][r] + bhv[j], 0.f);
        int k = j * 16 + l15;
        sA[m * 128 + (((k >> 3) ^ (m & 15)) * 8) + (k & 7)] = f32_to_bf16(v);
      }
  __syncthreads();

  // ---- GEMM2: out = hidden @ Wo (reuse acc) ----
#pragma unroll
  for (int i = 0; i < 2; ++i)
#pragma unroll
    for (int j = 0; j < 8; ++j) acc[i][j] = (f32x4){0.f, 0.f, 0.f, 0.f};

#pragma unroll
  for (int c = 0; c < 4; ++c) {
    int pu = ((c * 4 + l4) ^ l15) * 8;
    bf16x8 a0 = *(bf16x8*)&sA[m0 * 128 + pu];
    bf16x8 a1 = *(bf16x8*)&sA[m1 * 128 + pu];
#pragma unroll
    for (int j = 0; j < 8; ++j) {
      bf16x8 bfr = *(bf16x8*)&sW[(j * 16 + l15) * 128 + pu];
      acc[0][j] = __builtin_amdgcn_mfma_f32_16x16x32_bf16(a0, bfr, acc[0][j], 0, 0, 0);
      acc[1][j] = __builtin_amdgcn_mfma_f32_16x16x32_bf16(a1, bfr, acc[1][j], 0, 0, 0);
    }
  }

  __syncthreads();  // everyone done with sA/sW -> reuse as fp32 out stage

  // ---- epilogue: + bo, stage in LDS, coalesced dwordx4 stores ----
  float* sOut = (float*)smem;  // 128 x 128 fp32 = 64 KB
#pragma unroll
  for (int i = 0; i < 2; ++i)
#pragma unroll
    for (int j = 0; j < 8; ++j)
#pragma unroll
      for (int r = 0; r < 4; ++r) {
        int m = w * 32 + i * 16 + l4 * 4 + r;
        sOut[m * 128 + j * 16 + l15] = acc[i][j][r] + bov[j];
      }
  __syncthreads();
#pragma unroll
  for (int t = 0; t < 16; ++t) {
    int id = tid + t * 256;      // 0..4095 float4 units
    int r = id >> 5, u4 = id & 31;
    int gr = r0 + r;
    if (gr < nnodes)
      ((float4*)out)[(size_t)gr * 32 + u4] = ((const float4*)sOut)[id];
  }
}

// ---------------------------------------------------------------------------
extern "C" void kernel_launch(void* const* d_in, const int* in_sizes, int n_in,
                              void* d_out, int out_size, void* d_ws,
                              size_t ws_size, hipStream_t stream) {
  const float* X = (const float*)d_in[0];
  const int* ra = (const int*)d_in[1];
  const int* rb = (const int*)d_in[2];
  const float* Wh = (const float*)d_in[3];
  const float* bh = (const float*)d_in[4];
  const float* Wo = (const float*)d_in[5];
  const float* bo = (const float*)d_in[6];
  float* out = (float*)d_out;

  int nnodes = in_sizes[0] / 128;
  int nedges = in_sizes[1];

  // ws layout: [cnt: nnodes ints | adj: nnodes*CAP ints]
  // Xb (bf16 X) lives in d_out until mlp overwrites it (gather consumed it).
  // After gather: adj holds Xagg bf16 rows; cnt region dead -> WhT/WoT.
  int* cnt = (int*)d_ws;
  int* adj = cnt + nnodes;
  u16* WhT = (u16*)d_ws;
  u16* WoT = WhT + 16384;
  u16* Xb = (u16*)d_out;

  int n8 = nnodes * 16;  // 128 feats / 8 per thread
  hipMemsetAsync(cnt, 0, (size_t)nnodes * 4, stream);
  convert_x_kernel<<<(n8 + 255) / 256, 256, 0, stream>>>(X, Xb, n8);
  fill_adj_kernel<<<(2 * nedges + 255) / 256, 256, 0, stream>>>(ra, rb, cnt,
                                                                adj, nedges);
  gather_agg_kernel<<<(nnodes * 64 + 255) / 256, 256, 0, stream>>>(Xb, cnt,
                                                                   adj, nnodes);
  convert_w_kernel<<<128, 256, 0, stream>>>(Wh, Wo, WhT, WoT);
  mlp_mfma_kernel<<<(nnodes + 127) / 128, 256, 0, stream>>>(
      (const u16*)adj, WhT, WoT, bh, bo, out, nnodes);
}